// Round 11
// baseline (1784.780 us; speedup 1.0000x reference)
//
#include <hip/hip_runtime.h>
#include <math.h>

#define BB   4
#define NPTS 4096
#define NNODE (BB*NPTS)
#define CC   64
#define HHH  4
#define KK   16
#define D1   67
#define SD1  68     // padded row stride for xcat
#define SD2  64
#define NSTR 4      // candidate streams (= waves) per knn block
#define USTR (NSTR*KK + 2)   // per-node LDS merge stride (66 entries)

typedef __attribute__((ext_vector_type(2))) float f32x2;

// packed fp32 fma: a = b*c + a (elementwise on the pair). v_pk_fma_f32 is the
// 157.3TF-rate path on CDNA4; IEEE fp32 fma per component (== fmaf rounding).
__device__ __forceinline__ void pkfma(f32x2 &a, f32x2 b, f32x2 c){
    asm("v_pk_fma_f32 %0, %1, %2, %0" : "+v"(a) : "v"(b), "v"(c));
}

// ---------------------------------------------------------------- prep:
// build xcat fp32 [NNODE][68] = [features(64) | coords(3) | 0pad] and ||x||^2
__global__ __launch_bounds__(256) void k_prep(const float* __restrict__ pf,
                                              const float* __restrict__ pt,
                                              float* __restrict__ xcat,
                                              float* __restrict__ x2)
{
    int node = blockIdx.x*256 + threadIdx.x;
    int b = node >> 12, n = node & (NPTS-1);
    const float* pfb = pf + (size_t)b*CC*NPTS + n;
    const float* ptb = pt + (size_t)b*3*NPTS + n;
    float* row = xcat + (size_t)node*SD1;
    float acc = 0.f;
    #pragma unroll 8
    for (int c=0;c<CC;c++){ float v = pfb[(size_t)c*NPTS]; row[c]=v; acc = fmaf(v,v,acc); }
    #pragma unroll
    for (int c=0;c<3;c++){ float v = ptb[(size_t)c*NPTS]; row[CC+c]=v; acc = fmaf(v,v,acc); }
    row[SD1-1]=0.f;
    x2[node]=acc;
}

// ---------------------------------------------------------------- f64 key pack
// us = monotone uint of fp32 distance; key = us*4096 + local_idx (exact in f64).
// f64 '<' on keys == lex (d, idx), lowest index first == jax.lax.top_k tie-break.
__device__ __forceinline__ double packdi(float dd, int lidx){
    unsigned u = __float_as_uint(dd);
    unsigned us = u ^ ((unsigned)((int)u >> 31) | 0x80000000u);
    return fma((double)us, 4096.0, (double)lidx);
}

// branchless sorted-16 insert: 16-level min/max sift (no divergence)
__device__ __forceinline__ void sift16(double (&dk)[KK], double v){
    #pragma unroll
    for (int j=0;j<KK;j++){
        double lo = fmin(dk[j], v);
        v = fmax(dk[j], v);
        dk[j] = lo;
    }
}

// ---------------------------------------------------------------- fused knn (per segment)
// block = 256 threads = 4 waves, owns 64 consecutive nodes (node = base + lane),
// scans segment [seg*SEGC,(seg+1)*SEGC); wave w scans c ≡ w (mod 4) ascending.
// Candidate rows: per-lane VMEM loads at a wave-uniform address (TA merges to one
// L2 request), explicitly DOUBLE-BUFFERED (vmcnt is in-order -> compiler pipelines).
// Dot: v_pk_fma_f32, 2 packed chains == exact rounding of the previous 4-chain sum.
template<int SD, int NS>
__global__ __launch_bounds__(256) void k_knn_seg(const float* __restrict__ X,
    const float* __restrict__ x2, uint2* __restrict__ part)
{
    __shared__ unsigned       mus[64*USTR];   // 16896 B
    __shared__ unsigned short mix[64*USTR];   //  8448 B

    const int SEGC = NPTS/NS;
    const int QN   = SEGC/NSTR;               // candidates per stream (even)
    const int tid = threadIdx.x;
    const int w = tid>>6, l = tid&63;
    const int b = blockIdx.y, seg = blockIdx.z;
    const int nodeBase = b*NPTS + blockIdx.x*64;
    const int node = nodeBase + l;
    const int nlocal = blockIdx.x*64 + l;     // node index within batch

    // target row in registers as f32x2 pairs (68 VGPR)
    f32x2 xt[SD/2];
    {
        const f32x2* xr = (const f32x2*)(X + (size_t)node*SD);
        #pragma unroll
        for (int i=0;i<SD/2;i++) xt[i]=xr[i];
    }
    const float x2t = x2[node];

    double dk[KK];
    #pragma unroll
    for (int i=0;i<KK;i++) dk[i]=__builtin_inf();

    const float* Xb  = X  + (size_t)b*NPTS*SD;
    const float* x2b = x2 + (size_t)b*NPTS;
    const int lc0 = seg*SEGC + w;
    const float* rp = Xb + (size_t)lc0*SD;

    float4 bufA[SD/4], bufB[SD/4];
    float x2A, x2B;
    // prologue: load candidate q=0 into A
    #pragma unroll
    for (int i=0;i<SD/4;i++) bufA[i] = ((const float4*)rp)[i];
    x2A = x2b[lc0];

    #pragma unroll 1
    for (int q=0; q<QN; q+=2){
        // ---- issue B (candidate q+1): in flight during A's compute
        const float* rpB = rp + (size_t)NSTR*SD;
        #pragma unroll
        for (int i=0;i<SD/4;i++) bufB[i] = ((const float4*)rpB)[i];
        x2B = x2b[lc0 + (q+1)*NSTR];
        // ---- compute A (candidate q)
        {
            f32x2 a0 = {0.f,0.f}, a1 = {0.f,0.f};
            #pragma unroll
            for (int i=0;i<SD/4;i++){
                f32x2 lo; lo.x = bufA[i].x; lo.y = bufA[i].y;
                f32x2 hi; hi.x = bufA[i].z; hi.y = bufA[i].w;
                pkfma(a0, lo, xt[2*i]);
                pkfma(a1, hi, xt[2*i+1]);
            }
            float dot = (a0.x + a0.y) + (a1.x + a1.y);
            float dd = fmaf(-2.f, dot, x2t) + x2A;   // (x2_t - 2*dot) + x2_c
            int lc = lc0 + q*NSTR;
            double pd = packdi(dd, lc);
            if (lc==nlocal) pd = __builtin_inf();
            sift16(dk, pd);
        }
        // ---- issue A (candidate q+2), guarded against segment end
        {
            bool more = (q+2) < QN;
            const float* rpA2 = more ? rp + (size_t)2*NSTR*SD : rp;
            int lxA2 = more ? lc0 + (q+2)*NSTR : lc0;
            #pragma unroll
            for (int i=0;i<SD/4;i++) bufA[i] = ((const float4*)rpA2)[i];
            x2A = x2b[lxA2];
        }
        // ---- compute B (candidate q+1)
        {
            f32x2 a0 = {0.f,0.f}, a1 = {0.f,0.f};
            #pragma unroll
            for (int i=0;i<SD/4;i++){
                f32x2 lo; lo.x = bufB[i].x; lo.y = bufB[i].y;
                f32x2 hi; hi.x = bufB[i].z; hi.y = bufB[i].w;
                pkfma(a0, lo, xt[2*i]);
                pkfma(a1, hi, xt[2*i+1]);
            }
            float dot = (a0.x + a0.y) + (a1.x + a1.y);
            float dd = fmaf(-2.f, dot, x2t) + x2B;
            int lc = lc0 + (q+1)*NSTR;
            double pd = packdi(dd, lc);
            if (lc==nlocal) pd = __builtin_inf();
            sift16(dk, pd);
        }
        rp += (size_t)2*NSTR*SD;
    }

    // ---- publish sorted per-stream lists as (us, idx); exact unpack of keys
    #pragma unroll
    for (int i=0;i<KK;i++){
        double bd = dk[i];                       // finite: stream has >= 127 finite cands
        unsigned us = (unsigned)(bd * (1.0/4096.0));       // exact (pow2 scale, trunc)
        unsigned id = (unsigned)(bd - (double)us*4096.0);  // exact residual
        mus[l*USTR + w*KK + i] = us;
        mix[l*USTR + w*KK + i] = (unsigned short)id;
    }
    __syncthreads();
    // ---- serial 4-way merge, register heads: thread l (<64) owns node l
    if (tid < 64){
        const unsigned*       mu = mus + tid*USTR;
        const unsigned short* mi = mix + tid*USTR;
        unsigned hu[NSTR], hx[NSTR]; int pp[NSTR];
        #pragma unroll
        for (int s=0;s<NSTR;s++){ pp[s]=0; hu[s]=mu[s*KK]; hx[s]=mi[s*KK]; }
        size_t obase = ((size_t)(nodeBase + tid)*NS + seg)*KK;
        #pragma unroll 1
        for (int r=0;r<KK;r++){
            unsigned bu=hu[0], bx=hx[0]; int bw=0;
            #pragma unroll
            for (int s=1;s<NSTR;s++){
                if (hu[s]<bu || (hu[s]==bu && hx[s]<bx)){ bu=hu[s]; bx=hx[s]; bw=s; }
            }
            part[obase + r] = make_uint2(bu, bx);
            #pragma unroll
            for (int s=0;s<NSTR;s++){
                if (bw==s){
                    int np = ++pp[s];
                    bool ok = np < KK;
                    unsigned nu = mu[s*KK + np];   // np==KK reads pad; discarded
                    unsigned nx = mi[s*KK + np];
                    hu[s] = ok ? nu : 0xFFFFFFFFu;
                    hx[s] = ok ? nx : 0xFFFFu;
                }
            }
        }
    }
}

// ---------------------------------------------------------------- merge NS sorted uint2 lists -> nbr
template<int NS>
__global__ __launch_bounds__(256) void k_merge(const uint2* __restrict__ part,
    int* __restrict__ nbr)
{
    int node = blockIdx.x*256 + threadIdx.x;
    int bbase = (node >> 12) << 12;   // b*NPTS
    const uint2* p = part + (size_t)node*NS*KK;
    unsigned hu[NS], hx[NS]; int pp[NS];
    #pragma unroll
    for (int s=0;s<NS;s++){ pp[s]=0; uint2 v=p[s*KK]; hu[s]=v.x; hx[s]=v.y; }
    int obase = node*KK;
    #pragma unroll 1
    for (int r=0;r<KK;r++){
        unsigned bu=hu[0], bx=hx[0]; int bw=0;
        #pragma unroll
        for (int s=1;s<NS;s++){
            if (hu[s]<bu || (hu[s]==bu && hx[s]<bx)){ bu=hu[s]; bx=hx[s]; bw=s; }
        }
        nbr[obase + r] = bbase + (int)bx;
        #pragma unroll
        for (int s=0;s<NS;s++){
            if (bw==s){
                int np = ++pp[s];
                bool ok = np < KK;
                uint2 nv = p[s*KK + np];   // np==KK overreads 8B (slack-guarded)
                hu[s] = ok ? nv.x : 0xFFFFFFFFu;
                hx[s] = ok ? nv.y : 0xFFFFu;
            }
        }
    }
}

// ---------------------------------------------------------------- h = X@W, asrc, adst
template<int SD, int D>
__global__ __launch_bounds__(256) void k_gemm_h(const float* __restrict__ X,
    const float* __restrict__ W, const float* __restrict__ a_s,
    const float* __restrict__ a_d,
    float* __restrict__ h, float* __restrict__ asrc, float* __restrict__ adst)
{
    __shared__ float Wl[D*CC];
    __shared__ float asl[CC], adl[CC];
    const int tid = threadIdx.x;
    for (int i=tid;i<D*CC;i+=256) Wl[i]=W[i];
    if (tid<CC){ asl[tid]=a_s[tid]; adl[tid]=a_d[tid]; }
    __syncthreads();

    const int node = blockIdx.x*256 + tid;
    float xr[SD];
    const float4* xp = (const float4*)(X + (size_t)node*SD);
    #pragma unroll
    for (int i=0;i<SD/4;i++){ float4 v=xp[i]; xr[4*i]=v.x; xr[4*i+1]=v.y; xr[4*i+2]=v.z; xr[4*i+3]=v.w; }

    float sacc[HHH]={0,0,0,0}, dacc[HHH]={0,0,0,0};
    float* hrow = h + (size_t)node*CC;
    #pragma unroll 1
    for (int c4=0;c4<CC/4;c4++){
        float acc[4]={0,0,0,0};
        #pragma unroll
        for (int d=0;d<D;d++){
            const float* wp = Wl + d*CC + c4*4;
            float xv = xr[d];
            acc[0]=fmaf(xv,wp[0],acc[0]); acc[1]=fmaf(xv,wp[1],acc[1]);
            acc[2]=fmaf(xv,wp[2],acc[2]); acc[3]=fmaf(xv,wp[3],acc[3]);
        }
        int hh = c4 >> 2;
        #pragma unroll
        for (int j=0;j<4;j++){
            int c = c4*4+j;
            sacc[hh] = fmaf(acc[j], asl[c], sacc[hh]);
            dacc[hh] = fmaf(acc[j], adl[c], dacc[hh]);
        }
        ((float4*)hrow)[c4] = make_float4(acc[0],acc[1],acc[2],acc[3]);
    }
    #pragma unroll
    for (int q=0;q<HHH;q++){ asrc[(size_t)node*HHH+q]=sacc[q]; adst[(size_t)node*HHH+q]=dacc[q]; }
}

// ---------------------------------------------------------------- GAT gather+softmax+PV
__global__ __launch_bounds__(256) void k_gat(const float* __restrict__ h,
    const float* __restrict__ asrc, const float* __restrict__ adst,
    const int* __restrict__ nbr, const float* __restrict__ bias,
    float* __restrict__ f, float* __restrict__ x2out)
{
    int wid = threadIdx.x>>6, lane = threadIdx.x&63;
    int node = blockIdx.x*4 + wid;
    int hh = lane>>4;
    float ad = adst[(size_t)node*HHH+hh];
    int js[KK]; float e[KK];
    #pragma unroll
    for (int k=0;k<KK;k++){
        int j = nbr[node*KK+k] & (NNODE-1);    // clamp: garbage -> numeric error, never a fault
        js[k]=j;
        float ev = asrc[(size_t)j*HHH+hh] + ad;
        e[k] = ev>0.f ? ev : 0.2f*ev;          // leaky_relu 0.2
    }
    float m = e[0];
    #pragma unroll
    for (int k=1;k<KK;k++) m = fmaxf(m,e[k]);
    float s=0.f;
    #pragma unroll
    for (int k=0;k<KK;k++){ e[k]=__expf(e[k]-m); s+=e[k]; }
    float inv = 1.f/s;
    float acc=0.f;
    #pragma unroll
    for (int k=0;k<KK;k++)
        acc = fmaf(e[k]*inv, h[(size_t)js[k]*CC + lane], acc);
    float val = acc + bias[lane];
    val = val>0.f ? val : expm1f(val);          // elu
    f[(size_t)node*CC+lane]=val;
    float sq = val*val;
    #pragma unroll
    for (int s2=32;s2>0;s2>>=1) sq += __shfl_xor(sq, s2);
    if (lane==0) x2out[node]=sq;
}

// ---------------------------------------------------------------- final MLP + transpose-out
__global__ __launch_bounds__(256) void k_final(const float* __restrict__ f1,
    const float* __restrict__ f2, const float* __restrict__ Wm,
    const float* __restrict__ bm, float* __restrict__ out)
{
    __shared__ float Wl[2*CC*CC];   // 128x64 fp32 = 32 KB
    const int tid=threadIdx.x;
    for (int i=tid;i<2*CC*CC;i+=256) Wl[i]=Wm[i];
    __syncthreads();
    int node = blockIdx.x*256 + tid;
    int b = node>>12, n = node&(NPTS-1);
    float xr[2*CC];
    const float4* p1=(const float4*)(f1 + (size_t)node*CC);
    const float4* p2=(const float4*)(f2 + (size_t)node*CC);
    #pragma unroll
    for (int i=0;i<CC/4;i++){ float4 v=p1[i]; xr[4*i]=v.x; xr[4*i+1]=v.y; xr[4*i+2]=v.z; xr[4*i+3]=v.w; }
    #pragma unroll
    for (int i=0;i<CC/4;i++){ float4 v=p2[i]; xr[CC+4*i]=v.x; xr[CC+4*i+1]=v.y; xr[CC+4*i+2]=v.z; xr[CC+4*i+3]=v.w; }
    #pragma unroll 1
    for (int c4=0;c4<CC/4;c4++){
        float acc[4]={0,0,0,0};
        #pragma unroll
        for (int d=0;d<2*CC;d++){
            const float* wp = Wl + d*CC + c4*4;
            float xv=xr[d];
            acc[0]=fmaf(xv,wp[0],acc[0]); acc[1]=fmaf(xv,wp[1],acc[1]);
            acc[2]=fmaf(xv,wp[2],acc[2]); acc[3]=fmaf(xv,wp[3],acc[3]);
        }
        #pragma unroll
        for (int j=0;j<4;j++){
            int c=c4*4+j;
            float v = acc[j] + bm[c];
            v = v>0.f ? v : expm1f(v);
            out[(size_t)b*CC*NPTS + (size_t)c*NPTS + n] = v;
        }
    }
}

// ---------------------------------------------------------------- ws-too-small fallback
__global__ void k_zero(float* out, int n){
    int i = blockIdx.x*256 + threadIdx.x;
    if (i<n) out[i] = 0.f;
}

// ---------------------------------------------------------------- launcher
extern "C" void kernel_launch(void* const* d_in, const int* in_sizes, int n_in,
                              void* d_out, int out_size, void* d_ws, size_t ws_size,
                              hipStream_t stream) {
    const float* pf  = (const float*)d_in[0];
    const float* pt  = (const float*)d_in[1];
    const float* W1  = (const float*)d_in[2];
    const float* a1s = (const float*)d_in[3];
    const float* a1d = (const float*)d_in[4];
    const float* b1  = (const float*)d_in[5];
    const float* W2  = (const float*)d_in[6];
    const float* a2s = (const float*)d_in[7];
    const float* a2d = (const float*)d_in[8];
    const float* b2  = (const float*)d_in[9];
    const float* Wm  = (const float*)d_in[10];
    const float* bm  = (const float*)d_in[11];
    float* out = (float*)d_out;

    // ---- base workspace layout (floats), ~14.5 MB
    float* ws = (float*)d_ws;
    float* xcat  = ws;                             // 16384*68
    float* f2    = xcat;                           // alias (xcat dead after gemm1)
    float* h     = xcat + (size_t)NNODE*SD1;       // 16384*64
    float* f1    = h    + (size_t)NNODE*CC;        // 16384*64
    int*   nbr   = (int*)(f1 + (size_t)NNODE*CC);  // 16384*16
    float* x2    = (float*)(nbr + (size_t)NNODE*KK); // 16384
    float* asrc  = x2   + NNODE;                   // 16384*4
    float* adst  = asrc + (size_t)NNODE*HHH;       // 16384*4
    float* wsend = adst + (size_t)NNODE*HHH;
    size_t need_small = (size_t)(wsend - ws) * sizeof(float) + 64;
    size_t big_part_bytes = (size_t)NNODE*8*KK*sizeof(uint2);   // 16 MB
    size_t need_big = need_small + big_part_bytes + 64;

    if (ws_size < need_small) {   // diagnostic fallback: clean numeric fail, not a crash
        k_zero<<<(out_size+255)/256, 256, 0, stream>>>(out, out_size);
        return;
    }

    k_prep<<<NNODE/256, 256, 0, stream>>>(pf, pt, xcat, x2);

    if (ws_size >= need_big) {
        // ---- NSEG=8 path: 2048 blocks/knn, fresh 16 MB partials
        uint2* part = (uint2*)wsend;
        dim3 g(NPTS/64, BB, 8);
        k_knn_seg<SD1,8><<<g, 256, 0, stream>>>(xcat, x2, part);
        k_merge<8><<<NNODE/256, 256, 0, stream>>>(part, nbr);
        k_gemm_h<SD1, D1><<<NNODE/256, 256, 0, stream>>>(xcat, W1, a1s, a1d, h, asrc, adst);
        k_gat<<<NNODE/4, 256, 0, stream>>>(h, asrc, adst, nbr, b1, f1, x2);
        k_knn_seg<SD2,8><<<g, 256, 0, stream>>>(f1, x2, part);
        k_merge<8><<<NNODE/256, 256, 0, stream>>>(part, nbr);
    } else {
        // ---- NSEG=4 path (proven): partials (8 MB uint2) overlay dead regions
        uint2* part1 = (uint2*)h;      // over h+f1 (both rewritten after merge1)
        uint2* part2 = (uint2*)xcat;   // over xcat+h (xcat dead after gemm1)
        dim3 g(NPTS/64, BB, 4);
        k_knn_seg<SD1,4><<<g, 256, 0, stream>>>(xcat, x2, part1);
        k_merge<4><<<NNODE/256, 256, 0, stream>>>(part1, nbr);
        k_gemm_h<SD1, D1><<<NNODE/256, 256, 0, stream>>>(xcat, W1, a1s, a1d, h, asrc, adst);
        k_gat<<<NNODE/4, 256, 0, stream>>>(h, asrc, adst, nbr, b1, f1, x2);
        k_knn_seg<SD2,4><<<g, 256, 0, stream>>>(f1, x2, part2);
        k_merge<4><<<NNODE/256, 256, 0, stream>>>(part2, nbr);
    }

    k_gemm_h<SD2, CC><<<NNODE/256, 256, 0, stream>>>(f1, W2, a2s, a2d, h, asrc, adst);
    k_gat<<<NNODE/4, 256, 0, stream>>>(h, asrc, adst, nbr, b2, f2, x2);
    k_final<<<NNODE/256, 256, 0, stream>>>(f1, f2, Wm, bm, out);
}

// Round 12
// 815.429 us; speedup vs baseline: 2.1888x; 2.1888x over previous
//
#include <hip/hip_runtime.h>
#include <math.h>

#define BB   4
#define NPTS 4096
#define NNODE (BB*NPTS)
#define CC   64
#define HHH  4
#define KK   16
#define D1   67
#define SD1  68     // padded row stride for xcat
#define SD2  64
#define NSTR 4      // candidate streams (= waves) per knn block
#define USTR (NSTR*KK + 2)   // per-node LDS merge stride (66 entries)

typedef __attribute__((ext_vector_type(2))) float f32x2;

// packed fp32 fma: a.{lo,hi} += u.{lo,hi} * x.{lo,hi}. src0 is an SGPR pair
// (candidate row lives in SGPRs via scalarized uniform loads); VOP3P allows
// one SGPR source. IEEE fp32 fma per component == fmaf rounding.
__device__ __forceinline__ void pkfma_s(f32x2 &a, unsigned long long u, f32x2 x){
    asm("v_pk_fma_f32 %0, %1, %2, %0" : "+v"(a) : "s"(u), "v"(x));
}

// ---------------------------------------------------------------- prep:
// build xcat fp32 [NNODE][68] = [features(64) | coords(3) | 0pad] and ||x||^2
__global__ __launch_bounds__(256) void k_prep(const float* __restrict__ pf,
                                              const float* __restrict__ pt,
                                              float* __restrict__ xcat,
                                              float* __restrict__ x2)
{
    int node = blockIdx.x*256 + threadIdx.x;
    int b = node >> 12, n = node & (NPTS-1);
    const float* pfb = pf + (size_t)b*CC*NPTS + n;
    const float* ptb = pt + (size_t)b*3*NPTS + n;
    float* row = xcat + (size_t)node*SD1;
    float acc = 0.f;
    #pragma unroll 8
    for (int c=0;c<CC;c++){ float v = pfb[(size_t)c*NPTS]; row[c]=v; acc = fmaf(v,v,acc); }
    #pragma unroll
    for (int c=0;c<3;c++){ float v = ptb[(size_t)c*NPTS]; row[CC+c]=v; acc = fmaf(v,v,acc); }
    row[SD1-1]=0.f;
    x2[node]=acc;
}

// ---------------------------------------------------------------- f64 key pack
// us = monotone uint of fp32 distance; key = us*4096 + local_idx (exact in f64).
// f64 '<' on keys == lex (d, idx), lowest index first == jax.lax.top_k tie-break.
__device__ __forceinline__ double packdi(float dd, int lidx){
    unsigned u = __float_as_uint(dd);
    unsigned us = u ^ ((unsigned)((int)u >> 31) | 0x80000000u);
    return fma((double)us, 4096.0, (double)lidx);
}

// branchless sorted-16 insert: 16-level min/max sift (no divergence)
__device__ __forceinline__ void sift16(double (&dk)[KK], double v){
    #pragma unroll
    for (int j=0;j<KK;j++){
        double lo = fmin(dk[j], v);
        v = fmax(dk[j], v);
        dk[j] = lo;
    }
}

// ---------------------------------------------------------------- fused knn (per segment)
// block = 256 threads = 4 waves, owns 64 consecutive nodes (node = base + lane),
// scans candidate segment [seg*SEGC, (seg+1)*SEGC). wave w scans candidates
// c ≡ w (mod 4) ascending; rows are WAVE-UNIFORM -> scalar-pipe s_load into
// SGPRs; dot = v_pk_fma_f32 (SGPR src0), 2 packed chains == bit-identical to
// the 4-chain scalar sum of round 10. Per-lane sorted top-16 f64 keys ->
// (u32 us, u16 idx) in LDS -> block 4-way merge -> sorted uint2 16-list/segment.
template<int SD, int NS>
__global__ __launch_bounds__(256) void k_knn_seg(const float* __restrict__ X,
    const float* __restrict__ x2, uint2* __restrict__ part)
{
    __shared__ unsigned       mus[64*USTR];   // 16896 B
    __shared__ unsigned short mix[64*USTR];   //  8448 B   (25.3 KB total)

    const int SEGC = NPTS/NS;
    const int tid = threadIdx.x;
    const int w = __builtin_amdgcn_readfirstlane(tid>>6);  // wave id, uniform
    const int l = tid&63;
    const int b = blockIdx.y, seg = blockIdx.z;
    const int nodeBase = b*NPTS + blockIdx.x*64;
    const int node = nodeBase + l;
    const int nlocal = blockIdx.x*64 + l;   // node index within batch

    // target row in registers as f32x2 pairs (34 VGPR pairs)
    f32x2 xt[SD/2];
    {
        const f32x2* xr = (const f32x2*)(X + (size_t)node*SD);
        #pragma unroll
        for (int i=0;i<SD/2;i++) xt[i]=xr[i];
    }
    const float x2t = x2[node];

    double dk[KK];
    #pragma unroll
    for (int i=0;i<KK;i++) dk[i]=__builtin_inf();

    const float* Xb  = X  + (size_t)b*NPTS*SD;   // batch base (uniform)
    const float* x2b = x2 + (size_t)b*NPTS;

    #pragma unroll 1
    for (int q=0;q<SEGC/NSTR;q++){
        int lc = seg*SEGC + q*NSTR + w;          // local candidate idx (uniform)
        const unsigned long long* crow =
            (const unsigned long long*)(Xb + (size_t)lc*SD);   // uniform -> s_load
        float x2c = x2b[lc];                     // uniform -> s_load
        f32x2 a0 = {0.f,0.f}, a1 = {0.f,0.f};    // 2 packed chains == 4 scalar chains
        #pragma unroll
        for (int i=0;i<SD/4;i++){
            pkfma_s(a0, crow[2*i],   xt[2*i]);   // elems 4i+0,4i+1 -> chains {0,1}
            pkfma_s(a1, crow[2*i+1], xt[2*i+1]); // elems 4i+2,4i+3 -> chains {2,3}
        }
        float dot = (a0.x + a0.y) + (a1.x + a1.y);   // == (a0+a1)+(a2+a3)
        float dd = fmaf(-2.f, dot, x2t) + x2c;   // (x2_t - 2*dot) + x2_c
        double pd = packdi(dd, lc);
        if (lc==nlocal) pd = __builtin_inf();    // exclude self
        sift16(dk, pd);
    }
    // ---- publish sorted per-stream lists as (us, idx); exact unpack of keys
    #pragma unroll
    for (int i=0;i<KK;i++){
        double bd = dk[i];                       // finite: stream >= 127 finite cands
        unsigned us = (unsigned)(bd * (1.0/4096.0));       // exact (pow2 scale, trunc)
        unsigned id = (unsigned)(bd - (double)us*4096.0);  // exact residual
        mus[l*USTR + w*KK + i] = us;
        mix[l*USTR + w*KK + i] = (unsigned short)id;
    }
    __syncthreads();
    // ---- serial 4-way merge, register heads: thread l (<64) owns node l
    if (tid < 64){
        const unsigned*       mu = mus + tid*USTR;
        const unsigned short* mi = mix + tid*USTR;
        unsigned hu[NSTR], hx[NSTR]; int pp[NSTR];
        #pragma unroll
        for (int s=0;s<NSTR;s++){ pp[s]=0; hu[s]=mu[s*KK]; hx[s]=mi[s*KK]; }
        size_t obase = ((size_t)(nodeBase + tid)*NS + seg)*KK;
        #pragma unroll 1
        for (int r=0;r<KK;r++){
            unsigned bu=hu[0], bx=hx[0]; int bw=0;
            #pragma unroll
            for (int s=1;s<NSTR;s++){
                if (hu[s]<bu || (hu[s]==bu && hx[s]<bx)){ bu=hu[s]; bx=hx[s]; bw=s; }
            }
            part[obase + r] = make_uint2(bu, bx);
            #pragma unroll
            for (int s=0;s<NSTR;s++){
                if (bw==s){
                    int np = ++pp[s];
                    bool ok = np < KK;
                    unsigned nu = mu[s*KK + np];   // np==KK reads pad; discarded
                    unsigned nx = mi[s*KK + np];
                    hu[s] = ok ? nu : 0xFFFFFFFFu;
                    hx[s] = ok ? nx : 0xFFFFu;
                }
            }
        }
    }
}

// ---------------------------------------------------------------- merge NS sorted uint2 lists -> nbr
template<int NS>
__global__ __launch_bounds__(256) void k_merge(const uint2* __restrict__ part,
    int* __restrict__ nbr)
{
    int node = blockIdx.x*256 + threadIdx.x;
    int bbase = (node >> 12) << 12;   // b*NPTS
    const uint2* p = part + (size_t)node*NS*KK;
    unsigned hu[NS], hx[NS]; int pp[NS];
    #pragma unroll
    for (int s=0;s<NS;s++){ pp[s]=0; uint2 v=p[s*KK]; hu[s]=v.x; hx[s]=v.y; }
    int obase = node*KK;
    #pragma unroll 1
    for (int r=0;r<KK;r++){
        unsigned bu=hu[0], bx=hx[0]; int bw=0;
        #pragma unroll
        for (int s=1;s<NS;s++){
            if (hu[s]<bu || (hu[s]==bu && hx[s]<bx)){ bu=hu[s]; bx=hx[s]; bw=s; }
        }
        nbr[obase + r] = bbase + (int)bx;
        #pragma unroll
        for (int s=0;s<NS;s++){
            if (bw==s){
                int np = ++pp[s];
                bool ok = np < KK;
                uint2 nv = p[s*KK + np];   // np==KK overreads 8B (slack-guarded)
                hu[s] = ok ? nv.x : 0xFFFFFFFFu;
                hx[s] = ok ? nv.y : 0xFFFFu;
            }
        }
    }
}

// ---------------------------------------------------------------- h = X@W, asrc, adst
template<int SD, int D>
__global__ __launch_bounds__(256) void k_gemm_h(const float* __restrict__ X,
    const float* __restrict__ W, const float* __restrict__ a_s,
    const float* __restrict__ a_d,
    float* __restrict__ h, float* __restrict__ asrc, float* __restrict__ adst)
{
    __shared__ float Wl[D*CC];
    __shared__ float asl[CC], adl[CC];
    const int tid = threadIdx.x;
    for (int i=tid;i<D*CC;i+=256) Wl[i]=W[i];
    if (tid<CC){ asl[tid]=a_s[tid]; adl[tid]=a_d[tid]; }
    __syncthreads();

    const int node = blockIdx.x*256 + tid;
    float xr[SD];
    const float4* xp = (const float4*)(X + (size_t)node*SD);
    #pragma unroll
    for (int i=0;i<SD/4;i++){ float4 v=xp[i]; xr[4*i]=v.x; xr[4*i+1]=v.y; xr[4*i+2]=v.z; xr[4*i+3]=v.w; }

    float sacc[HHH]={0,0,0,0}, dacc[HHH]={0,0,0,0};
    float* hrow = h + (size_t)node*CC;
    #pragma unroll 1
    for (int c4=0;c4<CC/4;c4++){
        float acc[4]={0,0,0,0};
        #pragma unroll
        for (int d=0;d<D;d++){
            const float* wp = Wl + d*CC + c4*4;
            float xv = xr[d];
            acc[0]=fmaf(xv,wp[0],acc[0]); acc[1]=fmaf(xv,wp[1],acc[1]);
            acc[2]=fmaf(xv,wp[2],acc[2]); acc[3]=fmaf(xv,wp[3],acc[3]);
        }
        int hh = c4 >> 2;
        #pragma unroll
        for (int j=0;j<4;j++){
            int c = c4*4+j;
            sacc[hh] = fmaf(acc[j], asl[c], sacc[hh]);
            dacc[hh] = fmaf(acc[j], adl[c], dacc[hh]);
        }
        ((float4*)hrow)[c4] = make_float4(acc[0],acc[1],acc[2],acc[3]);
    }
    #pragma unroll
    for (int q=0;q<HHH;q++){ asrc[(size_t)node*HHH+q]=sacc[q]; adst[(size_t)node*HHH+q]=dacc[q]; }
}

// ---------------------------------------------------------------- GAT gather+softmax+PV
__global__ __launch_bounds__(256) void k_gat(const float* __restrict__ h,
    const float* __restrict__ asrc, const float* __restrict__ adst,
    const int* __restrict__ nbr, const float* __restrict__ bias,
    float* __restrict__ f, float* __restrict__ x2out)
{
    int wid = threadIdx.x>>6, lane = threadIdx.x&63;
    int node = blockIdx.x*4 + wid;
    int hh = lane>>4;
    float ad = adst[(size_t)node*HHH+hh];
    int js[KK]; float e[KK];
    #pragma unroll
    for (int k=0;k<KK;k++){
        int j = nbr[node*KK+k] & (NNODE-1);    // clamp: garbage -> numeric error, never a fault
        js[k]=j;
        float ev = asrc[(size_t)j*HHH+hh] + ad;
        e[k] = ev>0.f ? ev : 0.2f*ev;          // leaky_relu 0.2
    }
    float m = e[0];
    #pragma unroll
    for (int k=1;k<KK;k++) m = fmaxf(m,e[k]);
    float s=0.f;
    #pragma unroll
    for (int k=0;k<KK;k++){ e[k]=__expf(e[k]-m); s+=e[k]; }
    float inv = 1.f/s;
    float acc=0.f;
    #pragma unroll
    for (int k=0;k<KK;k++)
        acc = fmaf(e[k]*inv, h[(size_t)js[k]*CC + lane], acc);
    float val = acc + bias[lane];
    val = val>0.f ? val : expm1f(val);          // elu
    f[(size_t)node*CC+lane]=val;
    float sq = val*val;
    #pragma unroll
    for (int s2=32;s2>0;s2>>=1) sq += __shfl_xor(sq, s2);
    if (lane==0) x2out[node]=sq;
}

// ---------------------------------------------------------------- final MLP + transpose-out
__global__ __launch_bounds__(256) void k_final(const float* __restrict__ f1,
    const float* __restrict__ f2, const float* __restrict__ Wm,
    const float* __restrict__ bm, float* __restrict__ out)
{
    __shared__ float Wl[2*CC*CC];   // 128x64 fp32 = 32 KB
    const int tid=threadIdx.x;
    for (int i=tid;i<2*CC*CC;i+=256) Wl[i]=Wm[i];
    __syncthreads();
    int node = blockIdx.x*256 + tid;
    int b = node>>12, n = node&(NPTS-1);
    float xr[2*CC];
    const float4* p1=(const float4*)(f1 + (size_t)node*CC);
    const float4* p2=(const float4*)(f2 + (size_t)node*CC);
    #pragma unroll
    for (int i=0;i<CC/4;i++){ float4 v=p1[i]; xr[4*i]=v.x; xr[4*i+1]=v.y; xr[4*i+2]=v.z; xr[4*i+3]=v.w; }
    #pragma unroll
    for (int i=0;i<CC/4;i++){ float4 v=p2[i]; xr[CC+4*i]=v.x; xr[CC+4*i+1]=v.y; xr[CC+4*i+2]=v.z; xr[CC+4*i+3]=v.w; }
    #pragma unroll 1
    for (int c4=0;c4<CC/4;c4++){
        float acc[4]={0,0,0,0};
        #pragma unroll
        for (int d=0;d<2*CC;d++){
            const float* wp = Wl + d*CC + c4*4;
            float xv=xr[d];
            acc[0]=fmaf(xv,wp[0],acc[0]); acc[1]=fmaf(xv,wp[1],acc[1]);
            acc[2]=fmaf(xv,wp[2],acc[2]); acc[3]=fmaf(xv,wp[3],acc[3]);
        }
        #pragma unroll
        for (int j=0;j<4;j++){
            int c=c4*4+j;
            float v = acc[j] + bm[c];
            v = v>0.f ? v : expm1f(v);
            out[(size_t)b*CC*NPTS + (size_t)c*NPTS + n] = v;
        }
    }
}

// ---------------------------------------------------------------- ws-too-small fallback
__global__ void k_zero(float* out, int n){
    int i = blockIdx.x*256 + threadIdx.x;
    if (i<n) out[i] = 0.f;
}

// ---------------------------------------------------------------- launcher
extern "C" void kernel_launch(void* const* d_in, const int* in_sizes, int n_in,
                              void* d_out, int out_size, void* d_ws, size_t ws_size,
                              hipStream_t stream) {
    const float* pf  = (const float*)d_in[0];
    const float* pt  = (const float*)d_in[1];
    const float* W1  = (const float*)d_in[2];
    const float* a1s = (const float*)d_in[3];
    const float* a1d = (const float*)d_in[4];
    const float* b1  = (const float*)d_in[5];
    const float* W2  = (const float*)d_in[6];
    const float* a2s = (const float*)d_in[7];
    const float* a2d = (const float*)d_in[8];
    const float* b2  = (const float*)d_in[9];
    const float* Wm  = (const float*)d_in[10];
    const float* bm  = (const float*)d_in[11];
    float* out = (float*)d_out;

    // ---- base workspace layout (floats), ~14.5 MB
    float* ws = (float*)d_ws;
    float* xcat  = ws;                             // 16384*68
    float* f2    = xcat;                           // alias (xcat dead after gemm1)
    float* h     = xcat + (size_t)NNODE*SD1;       // 16384*64
    float* f1    = h    + (size_t)NNODE*CC;        // 16384*64
    int*   nbr   = (int*)(f1 + (size_t)NNODE*CC);  // 16384*16
    float* x2    = (float*)(nbr + (size_t)NNODE*KK); // 16384
    float* asrc  = x2   + NNODE;                   // 16384*4
    float* adst  = asrc + (size_t)NNODE*HHH;       // 16384*4
    float* wsend = adst + (size_t)NNODE*HHH;
    size_t need_small = (size_t)(wsend - ws) * sizeof(float) + 64;
    size_t big_part_bytes = (size_t)NNODE*8*KK*sizeof(uint2);   // 16 MB
    size_t need_big = need_small + big_part_bytes + 64;

    if (ws_size < need_small) {   // diagnostic fallback: clean numeric fail, not a crash
        k_zero<<<(out_size+255)/256, 256, 0, stream>>>(out, out_size);
        return;
    }

    k_prep<<<NNODE/256, 256, 0, stream>>>(pf, pt, xcat, x2);

    if (ws_size >= need_big) {
        // ---- NSEG=8 path: 2048 blocks/knn, fresh 16 MB partials
        uint2* part = (uint2*)wsend;
        dim3 g(NPTS/64, BB, 8);
        k_knn_seg<SD1,8><<<g, 256, 0, stream>>>(xcat, x2, part);
        k_merge<8><<<NNODE/256, 256, 0, stream>>>(part, nbr);
        k_gemm_h<SD1, D1><<<NNODE/256, 256, 0, stream>>>(xcat, W1, a1s, a1d, h, asrc, adst);
        k_gat<<<NNODE/4, 256, 0, stream>>>(h, asrc, adst, nbr, b1, f1, x2);
        k_knn_seg<SD2,8><<<g, 256, 0, stream>>>(f1, x2, part);
        k_merge<8><<<NNODE/256, 256, 0, stream>>>(part, nbr);
    } else {
        // ---- NSEG=4 path (proven): partials (8 MB uint2) overlay dead regions
        uint2* part1 = (uint2*)h;      // over h+f1 (both rewritten after merge1)
        uint2* part2 = (uint2*)xcat;   // over xcat+h (xcat dead after gemm1)
        dim3 g(NPTS/64, BB, 4);
        k_knn_seg<SD1,4><<<g, 256, 0, stream>>>(xcat, x2, part1);
        k_merge<4><<<NNODE/256, 256, 0, stream>>>(part1, nbr);
        k_gemm_h<SD1, D1><<<NNODE/256, 256, 0, stream>>>(xcat, W1, a1s, a1d, h, asrc, adst);
        k_gat<<<NNODE/4, 256, 0, stream>>>(h, asrc, adst, nbr, b1, f1, x2);
        k_knn_seg<SD2,4><<<g, 256, 0, stream>>>(f1, x2, part2);
        k_merge<4><<<NNODE/256, 256, 0, stream>>>(part2, nbr);
    }

    k_gemm_h<SD2, CC><<<NNODE/256, 256, 0, stream>>>(f1, W2, a2s, a2d, h, asrc, adst);
    k_gat<<<NNODE/4, 256, 0, stream>>>(h, asrc, adst, nbr, b2, f2, x2);
    k_final<<<NNODE/256, 256, 0, stream>>>(f1, f2, Wm, bm, out);
}

// Round 13
// 616.534 us; speedup vs baseline: 2.8949x; 1.3226x over previous
//
#include <hip/hip_runtime.h>
#include <math.h>

#define BB   4
#define NPTS 4096
#define NNODE (BB*NPTS)
#define CC   64
#define HHH  4
#define KK   16
#define D1   67
#define SD1  68     // padded row stride for xcat
#define SD2  64
#define NSTR 4      // candidate streams (= waves) per knn block
#define NSEG 8      // candidate segments
#define USTR (NSTR*KK + 2)   // per-node LDS merge stride (66 entries)

typedef __attribute__((ext_vector_type(2))) float f32x2;

// packed fp32 fma: a.{lo,hi} += u.{lo,hi} * x.{lo,hi}. src0 is an SGPR pair
// (candidate row lives in SGPRs via scalarized uniform loads); VOP3P allows
// one SGPR source. IEEE fp32 fma per component == fmaf rounding.
__device__ __forceinline__ void pkfma_s(f32x2 &a, unsigned long long u, f32x2 x){
    asm("v_pk_fma_f32 %0, %1, %2, %0" : "+v"(a) : "s"(u), "v"(x));
}

// ---------------------------------------------------------------- prep v2:
// 64 nodes/block via LDS transpose; grid NNODE/64 = 256 blocks.
// xcat fp32 [NNODE][68] = [features(64) | coords(3) | 0pad]; x2 computed in the
// EXACT serial fmaf order c=0..66 of the original (selection-critical).
__global__ __launch_bounds__(256) void k_prep(const float* __restrict__ pf,
                                              const float* __restrict__ pt,
                                              float* __restrict__ xcat,
                                              float* __restrict__ x2)
{
    __shared__ float T[64][69];   // stride 69: (5l+c)%32 -> conflict-free
    const int tid = threadIdx.x;
    const int nb = blockIdx.x*64;            // 64 | 4096 -> block within one batch
    const int b = nb>>12;
    const int n0 = nb & (NPTS-1);
    const int l = tid&63, w = tid>>6;
    const float* pfb = pf + (size_t)b*CC*NPTS + n0 + l;
    #pragma unroll
    for (int k=0;k<16;k++){ int c=w*16+k; T[l][c] = pfb[(size_t)c*NPTS]; }
    if (w<3)  T[l][64+w] = pt[(size_t)b*3*NPTS + (size_t)w*NPTS + n0 + l];
    if (w==3) T[l][67] = 0.f;
    __syncthreads();
    if (tid<64){
        float acc=0.f;
        #pragma unroll 1
        for (int c=0;c<67;c++){ float v=T[tid][c]; acc = fmaf(v,v,acc); }
        x2[nb+tid]=acc;
    }
    float* dst = xcat + (size_t)nb*SD1;      // contiguous 64*68 region
    for (int i=tid;i<64*SD1;i+=256) dst[i] = T[i/SD1][i%SD1];
}

// ---------------------------------------------------------------- f64 key pack
// us = monotone uint of fp32 distance; key = us*4096 + local_idx (exact in f64).
// f64 '<' on keys == lex (d, idx), lowest index first == jax.lax.top_k tie-break.
__device__ __forceinline__ double packdi(float dd, int lidx){
    unsigned u = __float_as_uint(dd);
    unsigned us = u ^ ((unsigned)((int)u >> 31) | 0x80000000u);
    return fma((double)us, 4096.0, (double)lidx);
}

// branchless sorted-16 insert: 16-level min/max sift (no divergence)
__device__ __forceinline__ void sift16(double (&dk)[KK], double v){
    #pragma unroll
    for (int j=0;j<KK;j++){
        double lo = fmin(dk[j], v);
        v = fmax(dk[j], v);
        dk[j] = lo;
    }
}

// ---------------------------------------------------------------- fused knn (per segment)
// UNCHANGED from round 12 (proven 274 us). block = 256 thr = 4 waves, 64 nodes;
// wave w scans c ≡ w (mod 4) ascending; rows wave-uniform -> s_load into SGPRs;
// dot = v_pk_fma_f32 (SGPR src0), bit-identical to the 4-chain scalar sum.
template<int SD, int NS>
__global__ __launch_bounds__(256) void k_knn_seg(const float* __restrict__ X,
    const float* __restrict__ x2, uint2* __restrict__ part)
{
    __shared__ unsigned       mus[64*USTR];
    __shared__ unsigned short mix[64*USTR];

    const int SEGC = NPTS/NS;
    const int tid = threadIdx.x;
    const int w = __builtin_amdgcn_readfirstlane(tid>>6);
    const int l = tid&63;
    const int b = blockIdx.y, seg = blockIdx.z;
    const int nodeBase = b*NPTS + blockIdx.x*64;
    const int node = nodeBase + l;
    const int nlocal = blockIdx.x*64 + l;

    f32x2 xt[SD/2];
    {
        const f32x2* xr = (const f32x2*)(X + (size_t)node*SD);
        #pragma unroll
        for (int i=0;i<SD/2;i++) xt[i]=xr[i];
    }
    const float x2t = x2[node];

    double dk[KK];
    #pragma unroll
    for (int i=0;i<KK;i++) dk[i]=__builtin_inf();

    const float* Xb  = X  + (size_t)b*NPTS*SD;
    const float* x2b = x2 + (size_t)b*NPTS;

    #pragma unroll 1
    for (int q=0;q<SEGC/NSTR;q++){
        int lc = seg*SEGC + q*NSTR + w;
        const unsigned long long* crow =
            (const unsigned long long*)(Xb + (size_t)lc*SD);   // uniform -> s_load
        float x2c = x2b[lc];
        f32x2 a0 = {0.f,0.f}, a1 = {0.f,0.f};
        #pragma unroll
        for (int i=0;i<SD/4;i++){
            pkfma_s(a0, crow[2*i],   xt[2*i]);
            pkfma_s(a1, crow[2*i+1], xt[2*i+1]);
        }
        float dot = (a0.x + a0.y) + (a1.x + a1.y);
        float dd = fmaf(-2.f, dot, x2t) + x2c;
        double pd = packdi(dd, lc);
        if (lc==nlocal) pd = __builtin_inf();
        sift16(dk, pd);
    }
    #pragma unroll
    for (int i=0;i<KK;i++){
        double bd = dk[i];
        unsigned us = (unsigned)(bd * (1.0/4096.0));
        unsigned id = (unsigned)(bd - (double)us*4096.0);
        mus[l*USTR + w*KK + i] = us;
        mix[l*USTR + w*KK + i] = (unsigned short)id;
    }
    __syncthreads();
    if (tid < 64){
        const unsigned*       mu = mus + tid*USTR;
        const unsigned short* mi = mix + tid*USTR;
        unsigned hu[NSTR], hx[NSTR]; int pp[NSTR];
        #pragma unroll
        for (int s=0;s<NSTR;s++){ pp[s]=0; hu[s]=mu[s*KK]; hx[s]=mi[s*KK]; }
        size_t obase = ((size_t)(nodeBase + tid)*NS + seg)*KK;
        #pragma unroll 1
        for (int r=0;r<KK;r++){
            unsigned bu=hu[0], bx=hx[0]; int bw=0;
            #pragma unroll
            for (int s=1;s<NSTR;s++){
                if (hu[s]<bu || (hu[s]==bu && hx[s]<bx)){ bu=hu[s]; bx=hx[s]; bw=s; }
            }
            part[obase + r] = make_uint2(bu, bx);
            #pragma unroll
            for (int s=0;s<NSTR;s++){
                if (bw==s){
                    int np = ++pp[s];
                    bool ok = np < KK;
                    unsigned nu = mu[s*KK + np];
                    unsigned nx = mi[s*KK + np];
                    hu[s] = ok ? nu : 0xFFFFFFFFu;
                    hx[s] = ok ? nx : 0xFFFFu;
                }
            }
        }
    }
}

// ---------------------------------------------------------------- h = X@W, asrc, adst (v2)
// 16 nodes/block, thread = (node g, c-quad cq); grid NNODE/16 = 1024 blocks.
// Per-c FMA chain keeps the exact serial-d order (h bits unchanged vs v1).
template<int SD, int D>
__global__ __launch_bounds__(256) void k_gemm_h(const float* __restrict__ X,
    const float* __restrict__ W, const float* __restrict__ a_s,
    const float* __restrict__ a_d,
    float* __restrict__ h, float* __restrict__ asrc, float* __restrict__ adst)
{
    __shared__ float Wl[D*CC];
    __shared__ float asl[CC], adl[CC];
    __shared__ float Xs[16][SD+1];
    const int tid = threadIdx.x;
    for (int i=tid;i<D*CC;i+=256) Wl[i]=W[i];
    if (tid<CC){ asl[tid]=a_s[tid]; adl[tid]=a_d[tid]; }
    const int nodeBase = blockIdx.x*16;
    {
        const float* src = X + (size_t)nodeBase*SD;   // contiguous 16*SD
        for (int i=tid;i<16*SD;i+=256) Xs[i/SD][i%SD] = src[i];
    }
    __syncthreads();
    const int g = tid>>4, cq = tid&15;
    const int node = nodeBase + g;
    float acc[4]={0,0,0,0};
    const float* xrow = Xs[g];
    #pragma unroll 1
    for (int d=0;d<D;d++){
        float xv = xrow[d];
        const float* wp = Wl + d*CC + cq*4;
        acc[0]=fmaf(xv,wp[0],acc[0]); acc[1]=fmaf(xv,wp[1],acc[1]);
        acc[2]=fmaf(xv,wp[2],acc[2]); acc[3]=fmaf(xv,wp[3],acc[3]);
    }
    ((float4*)(h + (size_t)node*CC))[cq] = make_float4(acc[0],acc[1],acc[2],acc[3]);
    float sp=0.f, dp=0.f;
    #pragma unroll
    for (int j=0;j<4;j++){
        int c = cq*4+j;
        sp = fmaf(acc[j], asl[c], sp);
        dp = fmaf(acc[j], adl[c], dp);
    }
    sp += __shfl_xor(sp,1); sp += __shfl_xor(sp,2);   // sum 4 c-quads of one head
    dp += __shfl_xor(dp,1); dp += __shfl_xor(dp,2);
    if ((cq&3)==0){
        asrc[(size_t)node*HHH + (cq>>2)] = sp;
        adst[(size_t)node*HHH + (cq>>2)] = dp;
    }
}

// ---------------------------------------------------------------- GAT: fused merge+gather+softmax+PV
// wave per node; 128 (us,idx) keys -> u64, 2/lane; 16 rounds of butterfly-min
// (== ascending lex (d,idx) order == the old serial merge). Then old gat math.
__global__ __launch_bounds__(256) void k_gat(const float* __restrict__ h,
    const float* __restrict__ asrc, const float* __restrict__ adst,
    const uint2* __restrict__ part, const float* __restrict__ bias,
    float* __restrict__ f, float* __restrict__ x2out)
{
    int wid = threadIdx.x>>6, lane = threadIdx.x&63;
    int node = blockIdx.x*4 + wid;
    int bbase = (node>>12)<<12;
    int hh = lane>>4;
    const uint2* pn = part + (size_t)node*(NSEG*KK);
    uint2 v0 = pn[lane], v1 = pn[64+lane];
    unsigned long long e0 = ((unsigned long long)v0.x<<16) | (unsigned long long)v0.y;
    unsigned long long e1 = ((unsigned long long)v1.x<<16) | (unsigned long long)v1.y;
    float ad = adst[(size_t)node*HHH+hh];
    int js[KK]; float e[KK];
    #pragma unroll 1
    for (int r=0;r<KK;r++){
        unsigned long long m = e0<e1 ? e0 : e1;
        #pragma unroll
        for (int s=32;s>0;s>>=1){
            unsigned long long o = __shfl_xor(m, s);
            if (o<m) m=o;
        }
        js[r] = bbase + (int)(m & 0xFFFFull);
        if (e0==m) e0 = ~0ull;     // keys unique: exactly one (lane,slot) matches
        if (e1==m) e1 = ~0ull;
    }
    #pragma unroll
    for (int k=0;k<KK;k++){
        int j = js[k] & (NNODE-1);             // safety clamp
        js[k]=j;
        float ev = asrc[(size_t)j*HHH+hh] + ad;
        e[k] = ev>0.f ? ev : 0.2f*ev;          // leaky_relu 0.2
    }
    float m = e[0];
    #pragma unroll
    for (int k=1;k<KK;k++) m = fmaxf(m,e[k]);
    float s=0.f;
    #pragma unroll
    for (int k=0;k<KK;k++){ e[k]=__expf(e[k]-m); s+=e[k]; }
    float inv = 1.f/s;
    float acc=0.f;
    #pragma unroll
    for (int k=0;k<KK;k++)
        acc = fmaf(e[k]*inv, h[(size_t)js[k]*CC + lane], acc);
    float val = acc + bias[lane];
    val = val>0.f ? val : expm1f(val);          // elu
    f[(size_t)node*CC+lane]=val;
    float sq = val*val;
    #pragma unroll
    for (int s2=32;s2>0;s2>>=1) sq += __shfl_xor(sq, s2);
    if (lane==0) x2out[node]=sq;
}

// ---------------------------------------------------------------- final MLP + transpose-out (v2)
// 16 nodes/block, thread = (node, c-quad); grid NNODE/16 = 1024 blocks.
__global__ __launch_bounds__(256) void k_final(const float* __restrict__ f1,
    const float* __restrict__ f2, const float* __restrict__ Wm,
    const float* __restrict__ bm, float* __restrict__ out)
{
    __shared__ float Wl[2*CC*CC];        // 32 KB
    __shared__ float Xs[16][2*CC+1];     // 8.25 KB
    const int tid=threadIdx.x;
    for (int i=tid;i<2*CC*CC;i+=256) Wl[i]=Wm[i];
    const int nodeBase = blockIdx.x*16;
    {
        const float* s1 = f1 + (size_t)nodeBase*CC;
        for (int i=tid;i<16*CC;i+=256) Xs[i/CC][i%CC] = s1[i];
        const float* s2 = f2 + (size_t)nodeBase*CC;
        for (int i=tid;i<16*CC;i+=256) Xs[i/CC][CC + i%CC] = s2[i];
    }
    __syncthreads();
    const int g = tid>>4, cq = tid&15;
    const int node = nodeBase + g;
    const int b = node>>12, n = node&(NPTS-1);
    float acc[4]={0,0,0,0};
    const float* xrow = Xs[g];
    #pragma unroll 1
    for (int d=0;d<2*CC;d++){
        float xv = xrow[d];
        const float* wp = Wl + d*CC + cq*4;
        acc[0]=fmaf(xv,wp[0],acc[0]); acc[1]=fmaf(xv,wp[1],acc[1]);
        acc[2]=fmaf(xv,wp[2],acc[2]); acc[3]=fmaf(xv,wp[3],acc[3]);
    }
    #pragma unroll
    for (int j=0;j<4;j++){
        int c = cq*4+j;
        float v = acc[j] + bm[c];
        v = v>0.f ? v : expm1f(v);
        out[(size_t)b*CC*NPTS + (size_t)c*NPTS + n] = v;
    }
}

// ---------------------------------------------------------------- ws-too-small fallback
__global__ void k_zero(float* out, int n){
    int i = blockIdx.x*256 + threadIdx.x;
    if (i<n) out[i] = 0.f;
}

// ---------------------------------------------------------------- launcher
extern "C" void kernel_launch(void* const* d_in, const int* in_sizes, int n_in,
                              void* d_out, int out_size, void* d_ws, size_t ws_size,
                              hipStream_t stream) {
    const float* pf  = (const float*)d_in[0];
    const float* pt  = (const float*)d_in[1];
    const float* W1  = (const float*)d_in[2];
    const float* a1s = (const float*)d_in[3];
    const float* a1d = (const float*)d_in[4];
    const float* b1  = (const float*)d_in[5];
    const float* W2  = (const float*)d_in[6];
    const float* a2s = (const float*)d_in[7];
    const float* a2d = (const float*)d_in[8];
    const float* b2  = (const float*)d_in[9];
    const float* Wm  = (const float*)d_in[10];
    const float* bm  = (const float*)d_in[11];
    float* out = (float*)d_out;

    // ---- workspace layout (floats), ~14.5 MB + 16 MB partials
    float* ws = (float*)d_ws;
    float* xcat  = ws;                             // 16384*68
    float* f2    = xcat;                           // alias (xcat dead after gemm1)
    float* h     = xcat + (size_t)NNODE*SD1;       // 16384*64
    float* f1    = h    + (size_t)NNODE*CC;        // 16384*64
    float* x2    = f1   + (size_t)NNODE*CC;        // 16384
    float* asrc  = x2   + NNODE;                   // 16384*4
    float* adst  = asrc + (size_t)NNODE*HHH;       // 16384*4
    float* wsend = adst + (size_t)NNODE*HHH;
    uint2* part  = (uint2*)wsend;                  // 16384*128 uint2 = 16 MB
    size_t need  = (size_t)(wsend - ws)*sizeof(float)
                 + (size_t)NNODE*NSEG*KK*sizeof(uint2) + 64;
    if (ws_size < need) {   // diagnostic fallback: clean numeric fail, not a crash
        k_zero<<<(out_size+255)/256, 256, 0, stream>>>(out, out_size);
        return;
    }

    dim3 knnGrid(NPTS/64, BB, NSEG);   // 2048 blocks x 256 thr

    k_prep<<<NNODE/64, 256, 0, stream>>>(pf, pt, xcat, x2);
    k_knn_seg<SD1,NSEG><<<knnGrid, 256, 0, stream>>>(xcat, x2, part);
    k_gemm_h<SD1, D1><<<NNODE/16, 256, 0, stream>>>(xcat, W1, a1s, a1d, h, asrc, adst);
    k_gat<<<NNODE/4, 256, 0, stream>>>(h, asrc, adst, part, b1, f1, x2);
    k_knn_seg<SD2,NSEG><<<knnGrid, 256, 0, stream>>>(f1, x2, part);
    k_gemm_h<SD2, CC><<<NNODE/16, 256, 0, stream>>>(f1, W2, a2s, a2d, h, asrc, adst);
    k_gat<<<NNODE/4, 256, 0, stream>>>(h, asrc, adst, part, b2, f2, x2);
    k_final<<<NNODE/16, 256, 0, stream>>>(f1, f2, Wm, bm, out);
}